// Round 10
// baseline (62.086 us; speedup 1.0000x reference)
//
#include <hip/hip_runtime.h>
#include <hip/hip_bf16.h>

// Problem constants:
//   X: (B=16, D=512, 60, 60) fp32 -> N = 3600
//   codewords: (K=32, D=512) fp32, scale: (K=32,) fp32
//   out E: (B, K, D) fp32
constexpr int BB = 16;
constexpr int DD = 512;
constexpr int NN = 3600;
constexpr int KK = 32;
constexpr int SBW = 57;    // 64-n windows per batch (56 full + 16-n tail)
constexpr int WIN = 64;

typedef __attribute__((ext_vector_type(8))) short short8;
typedef __attribute__((ext_vector_type(4))) float f32x4;

__device__ inline unsigned bf16pack(float a, float b) {
    unsigned ia = __float_as_uint(a), ib = __float_as_uint(b);
    ia = (ia + 0x7fffu + ((ia >> 16) & 1u)) >> 16;          // RNE to bf16
    ib = (ib + 0x7fffu + ((ib >> 16) & 1u)) & 0xffff0000u;
    return ia | ib;
}

__device__ inline int swzkey(int row) {      // XOR-swizzle key (elems, mult of 8)
    return ((row ^ (row >> 3)) & 7) << 3;
}

// ---------------------------------------------------------------------------
// K0: Cbf[k][d] = bf16(Cw[k][d]);  sc2[k] = scale[k]*sum_d C[k,d]^2
// ---------------------------------------------------------------------------
__global__ __launch_bounds__(256) void k0_prep(const float* __restrict__ Cw,
                                               const float* __restrict__ scale,
                                               ushort* __restrict__ Cbf,
                                               float* __restrict__ sc2) {
    __shared__ float buf[8][32];
    const int t = threadIdx.x;
    const int k = t & 31;
    const int h = t >> 5;   // 0..7, 64 d's each
    const float4* row = reinterpret_cast<const float4*>(Cw + k * DD + h * 64);
    uint2* crow = reinterpret_cast<uint2*>(Cbf + k * DD + h * 64);
    float s = 0.f;
#pragma unroll
    for (int j = 0; j < 16; ++j) {
        float4 v = row[j];
        crow[j] = make_uint2(bf16pack(v.x, v.y), bf16pack(v.z, v.w));
        s += v.x * v.x + v.y * v.y + v.z * v.z + v.w * v.w;
    }
    buf[h][k] = s;
    __syncthreads();
    if (t < 32) {
        float tot = 0.f;
#pragma unroll
        for (int j = 0; j < 8; ++j) tot += buf[j][t];
        sc2[t] = scale[t] * tot;
    }
}

// ---------------------------------------------------------------------------
// KF: fused GEMM1 + softmax + GEMM2 over a 64-n window.
// Grid: B*SBW = 912 blocks x 256 threads (4 waves); LDS ~73 KB -> 2 blocks/CU
// resident, so one block's staging overlaps the other's compute phases.
// 4 chunks of 128 d, counted-vmcnt pipeline (raw s_barrier, lgkmcnt-only).
// Out: Ep bf16 partials [b][sb][k][d] + asum partials.
// ---------------------------------------------------------------------------
__global__ __launch_bounds__(256, 2) void kf_fused(const float* __restrict__ X,
                                                   const ushort* __restrict__ Cbf,
                                                   const float* __restrict__ scale,
                                                   const float* __restrict__ sc2,
                                                   ushort* __restrict__ Epb,
                                                   float* __restrict__ asum_part) {
    __shared__ ushort tile[DD * WIN];     // 64 KB, XOR-swizzled rows
    __shared__ ushort As2[KK * WIN];      // 4 KB, same swizzle per k-row
    __shared__ float x2part[16][WIN];     // 4 KB
    __shared__ float x2s[WIN];
    __shared__ float asw[4][KK];

    const int t = threadIdx.x;
    const int w = t >> 6;     // wave 0..3
    const int l = t & 63;
    const int q = l >> 4;     // 0..3
    const int r = l & 15;     // 0..15
    const int ng = t & 15;    // staging n-group (4 n)
    const int dd = t >> 4;    // staging d-subgroup 0..15
    const int b = blockIdx.x / SBW;
    const int sb = blockIdx.x % SBW;
    const int n0 = sb * WIN;
    const float* Xb = X + (size_t)b * DD * NN;
    const ushort* cb0 = Cbf + r * DD + q * 8;
    const ushort* cb1 = cb0 + 16 * DD;

    int nst = n0 + ng * 4;
    if (nst > NN - 4) nst = NN - 4;
    const float* xsrc = Xb + nst;

    const int nloc = w * 16 + r;          // phase-A A-frag row (n)
    f32x4 a0 = {0.f, 0.f, 0.f, 0.f};
    f32x4 a1 = {0.f, 0.f, 0.f, 0.f};
    float x2loc[4] = {0.f, 0.f, 0.f, 0.f};

    float4 bufA[8], bufB[8];
#pragma unroll
    for (int i = 0; i < 8; ++i)
        bufA[i] = *reinterpret_cast<const float4*>(xsrc + (size_t)(dd * 8 + i) * NN);

    // One chunk = 128 d rows staged + 4 MFMA steps. C-frag loads issued first
    // (oldest) so the MFMA's vmcnt wait leaves the next-chunk prefetch flying.
#define CHUNK_BODY(CURB, NXTB, C)                                              \
    {                                                                          \
        short8 cf0[4], cf1[4];                                                 \
        _Pragma("unroll")                                                      \
        for (int u = 0; u < 4; ++u) {                                          \
            cf0[u] = *reinterpret_cast<const short8*>(cb0 + ((C)*4 + u) * 32); \
            cf1[u] = *reinterpret_cast<const short8*>(cb1 + ((C)*4 + u) * 32); \
        }                                                                      \
        if ((C) < 3) {                                                         \
            _Pragma("unroll")                                                  \
            for (int i = 0; i < 8; ++i)                                        \
                NXTB[i] = *reinterpret_cast<const float4*>(                    \
                    xsrc + (size_t)(((C) + 1) * 128 + dd * 8 + i) * NN);       \
        }                                                                      \
        _Pragma("unroll")                                                      \
        for (int i = 0; i < 8; ++i) {                                          \
            const float4 v = CURB[i];                                          \
            x2loc[0] = fmaf(v.x, v.x, x2loc[0]);                               \
            x2loc[1] = fmaf(v.y, v.y, x2loc[1]);                               \
            x2loc[2] = fmaf(v.z, v.z, x2loc[2]);                               \
            x2loc[3] = fmaf(v.w, v.w, x2loc[3]);                               \
            const int d = (C) * 128 + dd * 8 + i;                              \
            *reinterpret_cast<uint2*>(                                         \
                &tile[d * WIN + ((ng * 4) ^ swzkey(d))]) =                     \
                make_uint2(bf16pack(v.x, v.y), bf16pack(v.z, v.w));            \
        }                                                                      \
        asm volatile("s_waitcnt lgkmcnt(0)" ::: "memory");                     \
        __builtin_amdgcn_s_barrier();                                          \
        __builtin_amdgcn_sched_barrier(0);                                     \
        _Pragma("unroll")                                                      \
        for (int u = 0; u < 4; ++u) {                                          \
            const int s = (C) * 4 + u;                                         \
            union { short8 s8; ushort us[8]; } af;                             \
            _Pragma("unroll")                                                  \
            for (int jj = 0; jj < 8; ++jj) {                                   \
                const int dA = s * 32 + q * 8 + jj;                            \
                af.us[jj] = tile[dA * WIN + (nloc ^ swzkey(dA))];              \
            }                                                                  \
            a0 = __builtin_amdgcn_mfma_f32_16x16x32_bf16(af.s8, cf0[u], a0, 0, 0, 0); \
            a1 = __builtin_amdgcn_mfma_f32_16x16x32_bf16(af.s8, cf1[u], a1, 0, 0, 0); \
        }                                                                      \
    }

    CHUNK_BODY(bufA, bufB, 0)
    CHUNK_BODY(bufB, bufA, 1)
    CHUNK_BODY(bufA, bufB, 2)
    CHUNK_BODY(bufB, bufA, 3)
#undef CHUNK_BODY

    // ---- x2 reduction (fp32 exact) ----
    *reinterpret_cast<f32x4*>(&x2part[dd][ng * 4]) =
        (f32x4){x2loc[0], x2loc[1], x2loc[2], x2loc[3]};
    __syncthreads();   // no vmem in flight now -> drain harmless
    if (t < WIN) {
        float s = 0.f;
#pragma unroll
        for (int dg = 0; dg < 16; ++dg) s += x2part[dg][t];
        x2s[t] = s;
    }
    __syncthreads();

    // ---- softmax (lane (q,r): n = w*16 + 4q + i, k = r / r+16) ----
    const float sk0 = scale[r], sk1 = scale[r + 16];
    const float sq0 = sc2[r],  sq1 = sc2[r + 16];
    float e0v[4], e1v[4];
    float as0 = 0.f, as1 = 0.f;
#pragma unroll
    for (int i = 0; i < 4; ++i) {
        const float x2v = x2s[w * 16 + 4 * q + i];
        float sl0 = fmaf(sk0, x2v, sq0) - 2.f * sk0 * a0[i];
        float sl1 = fmaf(sk1, x2v, sq1) - 2.f * sk1 * a1[i];
        float m = fmaxf(sl0, sl1);
        m = fmaxf(m, __shfl_xor(m, 1));
        m = fmaxf(m, __shfl_xor(m, 2));
        m = fmaxf(m, __shfl_xor(m, 4));
        m = fmaxf(m, __shfl_xor(m, 8));
        float e0 = __expf(sl0 - m), e1 = __expf(sl1 - m);
        float ssum = e0 + e1;
        ssum += __shfl_xor(ssum, 1);
        ssum += __shfl_xor(ssum, 2);
        ssum += __shfl_xor(ssum, 4);
        ssum += __shfl_xor(ssum, 8);
        const float inv = 1.f / ssum;
        e0 *= inv; e1 *= inv;
        if (n0 + w * 16 + 4 * q + i >= NN) { e0 = 0.f; e1 = 0.f; }
        e0v[i] = e0; e1v[i] = e1;
        as0 += e0; as1 += e1;
    }
    *reinterpret_cast<uint2*>(&As2[r * WIN + ((w * 16 + 4 * q) ^ swzkey(r))]) =
        make_uint2(bf16pack(e0v[0], e0v[1]), bf16pack(e0v[2], e0v[3]));
    *reinterpret_cast<uint2*>(&As2[(r + 16) * WIN + ((w * 16 + 4 * q) ^ swzkey(r + 16))]) =
        make_uint2(bf16pack(e1v[0], e1v[1]), bf16pack(e1v[2], e1v[3]));

    as0 += __shfl_xor(as0, 16); as0 += __shfl_xor(as0, 32);
    as1 += __shfl_xor(as1, 16); as1 += __shfl_xor(as1, 32);
    if (l < 16) { asw[w][r] = as0; asw[w][r + 16] = as1; }
    __syncthreads();   // As2 + asw visible to all waves
    if (t < KK) {
        float s = 0.f;
#pragma unroll
        for (int jw = 0; jw < 4; ++jw) s += asw[jw][t];
        asum_part[((size_t)b * SBW + sb) * KK + t] = s;
    }

    // ---- phase B: GEMM2; wave w owns d in [w*128, w*128+128) ----
    short8 bfr0[2], bfr1[2];
#pragma unroll
    for (int step = 0; step < 2; ++step) {
        bfr0[step] = *reinterpret_cast<const short8*>(
            &As2[r * WIN + ((step * 32 + q * 8) ^ swzkey(r))]);
        bfr1[step] = *reinterpret_cast<const short8*>(
            &As2[(r + 16) * WIN + ((step * 32 + q * 8) ^ swzkey(r + 16))]);
    }

    f32x4 acc[8][2];
#pragma unroll
    for (int df = 0; df < 8; ++df) {
        acc[df][0] = (f32x4){0.f, 0.f, 0.f, 0.f};
        acc[df][1] = (f32x4){0.f, 0.f, 0.f, 0.f};
    }

#pragma unroll
    for (int df = 0; df < 8; ++df) {
        const int d = w * 128 + df * 16 + r;   // A-frag row
        const int kd = swzkey(d);
#pragma unroll
        for (int step = 0; step < 2; ++step) {
            const short8 xa = *reinterpret_cast<const short8*>(
                &tile[d * WIN + ((step * 32 + q * 8) ^ kd)]);
            acc[df][0] = __builtin_amdgcn_mfma_f32_16x16x32_bf16(
                xa, bfr0[step], acc[df][0], 0, 0, 0);
            acc[df][1] = __builtin_amdgcn_mfma_f32_16x16x32_bf16(
                xa, bfr1[step], acc[df][1], 0, 0, 0);
        }
    }

    // ---- store Ep partial (bf16): D-frag rows q*4+i are d-contiguous ----
    ushort* ep = Epb + (size_t)(b * SBW + sb) * KK * DD;
#pragma unroll
    for (int df = 0; df < 8; ++df) {
#pragma unroll
        for (int kf = 0; kf < 2; ++kf) {
            const int k = kf * 16 + r;
            const int d = w * 128 + df * 16 + q * 4;
            const f32x4 v = acc[df][kf];
            *reinterpret_cast<uint2*>(ep + (size_t)k * DD + d) =
                make_uint2(bf16pack(v[0], v[1]), bf16pack(v[2], v[3]));
        }
    }
}

// ---------------------------------------------------------------------------
// K3: E[b,k,d] = sum_sb bf16(Ep[b,sb,k,d]) - Asum[b,k]*C[k,d]
// Grid: B*K = 512 blocks x 256 threads (2 d's per thread, packed uint reads).
// ---------------------------------------------------------------------------
__global__ __launch_bounds__(256) void k3_final(const ushort* __restrict__ Epb,
                                                const float* __restrict__ asum_part,
                                                const float* __restrict__ Cw,
                                                float* __restrict__ E) {
    const int t = threadIdx.x;
    const int b = blockIdx.x >> 5, k = blockIdx.x & 31;

    float asum = 0.f;
#pragma unroll
    for (int sb = 0; sb < SBW; ++sb)
        asum += asum_part[((size_t)b * SBW + sb) * KK + k];

    const int d = t * 2;
    float s0 = 0.f, s1 = 0.f;
#pragma unroll 4
    for (int sb = 0; sb < SBW; ++sb) {
        const unsigned u = *reinterpret_cast<const unsigned*>(
            Epb + (((size_t)b * SBW + sb) * KK + k) * DD + d);
        s0 += __uint_as_float(u << 16);
        s1 += __uint_as_float(u & 0xffff0000u);
    }
    float2 c = *reinterpret_cast<const float2*>(Cw + k * DD + d);
    float2 o;
    o.x = s0 - asum * c.x;
    o.y = s1 - asum * c.y;
    *reinterpret_cast<float2*>(E + ((size_t)b * KK + k) * DD + d) = o;
}

// ---------------------------------------------------------------------------
extern "C" void kernel_launch(void* const* d_in, const int* in_sizes, int n_in,
                              void* d_out, int out_size, void* d_ws, size_t ws_size,
                              hipStream_t stream) {
    const float* X     = (const float*)d_in[0];
    const float* Cw    = (const float*)d_in[1];
    const float* scale = (const float*)d_in[2];
    float* E = (float*)d_out;

    // ws layout:
    //   Epb       : 16*57*32*512 ushort = 14,942,208 u16 (~29.9 MB)
    //   asum_part : 912*32 float
    //   sc2       : 32 float
    //   Cbf       : 32*512 ushort
    float* ws = (float*)d_ws;
    ushort* Epb = (ushort*)ws;
    float* asum_part = ws + (size_t)BB * SBW * KK * DD / 2;
    float* sc2 = asum_part + (size_t)BB * SBW * KK;
    ushort* Cbf = (ushort*)(sc2 + KK);

    k0_prep<<<dim3(1), dim3(256), 0, stream>>>(Cw, scale, Cbf, sc2);
    kf_fused<<<dim3(BB * SBW), dim3(256), 0, stream>>>(X, Cbf, scale, sc2, Epb, asum_part);
    k3_final<<<dim3(BB * KK), dim3(256), 0, stream>>>(Epb, asum_part, Cw, E);
}